// Round 1
// baseline (5224.816 us; speedup 1.0000x reference)
//
#include <hip/hip_runtime.h>
#include <math.h>

#define NN 100000
#define TT 512
#define EE 1024
#define NSTEP (TT - 1)              // 511
#define MU 0.05f
#define RHO 32.0f
#define CAP (NSTEP * EE * 2)        // 1,046,528 max list entries

__device__ __forceinline__ float sigmoid_f(float x) {
    return 1.0f / (1.0f + expf(-x));
}

// Phase 0: X = sigmoid(logit), write output row 0, zero count/cursor.
__global__ void k_init(const float* __restrict__ logit, float* __restrict__ X,
                       float* __restrict__ out, int* __restrict__ cnt,
                       int* __restrict__ cur) {
    int n = blockIdx.x * blockDim.x + threadIdx.x;
    if (n < NN) {
        float x = sigmoid_f(logit[n]);
        X[n] = x;
        out[n] = x;          // row 0 of X output
        cnt[n] = 0;
        cur[n] = 0;
    }
}

// Phase 0b: count per-node appends (only s==1 edges can modify state).
__global__ void k_count(const int* __restrict__ edges, int* __restrict__ cnt) {
    int i = blockIdx.x * blockDim.x + threadIdx.x;
    if (i < NSTEP * EE) {
        int s = edges[3 * i + 2];
        if (s) {
            atomicAdd(&cnt[edges[3 * i + 0]], 1);
            atomicAdd(&cnt[edges[3 * i + 1]], 1);
        }
    }
}

// Phase 0c: exclusive prefix sum over cnt -> off. Single block, 1024 threads.
__global__ void __launch_bounds__(1024) k_scan(const int* __restrict__ cnt,
                                               int* __restrict__ off) {
    __shared__ int sh[1024];
    int tid = threadIdx.x;
    const int seg = (NN + 1023) / 1024;   // 98
    int lo = tid * seg;
    int hi = lo + seg; if (hi > NN) hi = NN;
    int s = 0;
    for (int i = lo; i < hi; ++i) s += cnt[i];
    sh[tid] = s;
    __syncthreads();
    // Hillis-Steele inclusive scan over the 1024 partial sums
    for (int o = 1; o < 1024; o <<= 1) {
        int v = (tid >= o) ? sh[tid - o] : 0;
        __syncthreads();
        sh[tid] += v;
        __syncthreads();
    }
    int base = sh[tid] - s;               // exclusive
    for (int i = lo; i < hi; ++i) {
        off[i] = base;
        base += cnt[i];
    }
}

// Phase 1: the sequential scan. One block, 1024 threads (1 thread = 1 edge).
// Per step: gather X (L2-coherent loads), kappa, barrier, atomic update,
// append (step, delta) to per-node time-ordered lists, barrier.
__global__ void __launch_bounds__(1024) k_seq(const int* __restrict__ edges,
                                              const float* __restrict__ theta,
                                              float* __restrict__ X,
                                              float* __restrict__ out_kappa,
                                              const int* __restrict__ off,
                                              int* __restrict__ cur,
                                              int* __restrict__ steps,
                                              float* __restrict__ deltas) {
    const int tid = threadIdx.x;
    const float eps = sigmoid_f(theta[0]);
    for (int t = 0; t < NSTEP; ++t) {
        const int base = t * 3 * EE + 3 * tid;
        int u = edges[base + 0];
        int v = edges[base + 1];
        int s = edges[base + 2];
        // L2-coherent loads: updates are L2 atomics, plain loads could hit
        // stale L1 lines.
        float xu = __hip_atomic_load(&X[u], __ATOMIC_RELAXED, __HIP_MEMORY_SCOPE_AGENT);
        float xv = __hip_atomic_load(&X[v], __ATOMIC_RELAXED, __HIP_MEMORY_SCOPE_AGENT);
        float diff = xu - xv;
        out_kappa[t * EE + tid] = sigmoid_f(RHO * (eps - fabsf(diff)));
        __syncthreads();   // all gathers done before any update lands
        if (s && diff != 0.0f) {
            float md = MU * diff;
            atomicAdd(&X[u], -md);
            atomicAdd(&X[v],  md);
            int pu = off[u] + atomicAdd(&cur[u], 1);
            steps[pu] = t; deltas[pu] = -md;
            int pv = off[v] + atomicAdd(&cur[v], 1);
            steps[pv] = t; deltas[pv] =  md;
        }
        __syncthreads();   // updates drained to L2 before next gather
    }
}

// Phase 2: reconstruct rows 1..511. One thread per node walks its delta list;
// stores are fully coalesced across the block (consecutive n, same row).
__global__ void k_fill(float* __restrict__ out,
                       const int* __restrict__ off, const int* __restrict__ cur,
                       const int* __restrict__ steps,
                       const float* __restrict__ deltas) {
    int n = blockIdx.x * blockDim.x + threadIdx.x;
    if (n >= NN) return;
    float val = out[n];                   // X0[n] from row 0
    int p = off[n];
    int e = p + cur[n];
    int nxt = (p < e) ? steps[p] : 0x7fffffff;
    for (int r = 1; r < TT; ++r) {
        while (nxt < r) {                 // apply updates of step r-1
            val += deltas[p];
            ++p;
            nxt = (p < e) ? steps[p] : 0x7fffffff;
        }
        out[(size_t)r * NN + n] = val;
    }
}

extern "C" void kernel_launch(void* const* d_in, const int* in_sizes, int n_in,
                              void* d_out, int out_size, void* d_ws, size_t ws_size,
                              hipStream_t stream) {
    const float* logit = (const float*)d_in[0];
    const float* theta = (const float*)d_in[1];
    const int*   edges = (const int*)d_in[2];
    float* out = (float*)d_out;

    char* ws = (char*)d_ws;
    float* X    = (float*)ws;  ws += sizeof(float) * NN;
    int*   cnt  = (int*)ws;    ws += sizeof(int) * NN;
    int*   off  = (int*)ws;    ws += sizeof(int) * NN;
    int*   cur  = (int*)ws;    ws += sizeof(int) * NN;
    int*   stp  = (int*)ws;    ws += sizeof(int) * CAP;
    float* dels = (float*)ws;  ws += sizeof(float) * CAP;

    k_init<<<(NN + 255) / 256, 256, 0, stream>>>(logit, X, out, cnt, cur);
    k_count<<<(NSTEP * EE + 255) / 256, 256, 0, stream>>>(edges, cnt);
    k_scan<<<1, 1024, 0, stream>>>(cnt, off);
    k_seq<<<1, 1024, 0, stream>>>(edges, theta, X, out + (size_t)TT * NN,
                                  off, cur, stp, dels);
    k_fill<<<(NN + 255) / 256, 256, 0, stream>>>(out, off, cur, stp, dels);
}

// Round 2
// 5111.404 us; speedup vs baseline: 1.0222x; 1.0222x over previous
//
#include <hip/hip_runtime.h>
#include <math.h>

#define NN 100000
#define TT 512
#define EE 1024
#define NSTEP (TT - 1)              // 511
#define MU 0.05f
#define RHO 32.0f
#define CAP (NSTEP * EE * 2)        // 1,046,528 max list entries

#define WG __HIP_MEMORY_SCOPE_WORKGROUP
#define RLX __ATOMIC_RELAXED

__device__ __forceinline__ float sigmoid_f(float x) {
    return 1.0f / (1.0f + expf(-x));
}

// Phase 0: X = sigmoid(logit), write output row 0, zero count/cursor.
__global__ void k_init(const float* __restrict__ logit, float* __restrict__ X,
                       float* __restrict__ out, int* __restrict__ cnt,
                       int* __restrict__ cur) {
    int n = blockIdx.x * blockDim.x + threadIdx.x;
    if (n < NN) {
        float x = sigmoid_f(logit[n]);
        X[n] = x;
        out[n] = x;          // row 0 of X output
        cnt[n] = 0;
        cur[n] = 0;
    }
}

// Phase 0b: count per-node appends (only s==1 edges can modify state).
__global__ void k_count(const int* __restrict__ edges, int* __restrict__ cnt) {
    int i = blockIdx.x * blockDim.x + threadIdx.x;
    if (i < NSTEP * EE) {
        int s = edges[3 * i + 2];
        if (s) {
            atomicAdd(&cnt[edges[3 * i + 0]], 1);
            atomicAdd(&cnt[edges[3 * i + 1]], 1);
        }
    }
}

// Phase 0c: exclusive prefix sum over cnt -> off. Single block, 1024 threads.
__global__ void __launch_bounds__(1024) k_scan(const int* __restrict__ cnt,
                                               int* __restrict__ off) {
    __shared__ int sh[1024];
    int tid = threadIdx.x;
    const int seg = (NN + 1023) / 1024;   // 98
    int lo = tid * seg;
    int hi = lo + seg; if (hi > NN) hi = NN;
    int s = 0;
    for (int i = lo; i < hi; ++i) s += cnt[i];
    sh[tid] = s;
    __syncthreads();
    // Hillis-Steele inclusive scan over the 1024 partial sums
    for (int o = 1; o < 1024; o <<= 1) {
        int v = (tid >= o) ? sh[tid - o] : 0;
        __syncthreads();
        sh[tid] += v;
        __syncthreads();
    }
    int base = sh[tid] - s;               // exclusive
    for (int i = lo; i < hi; ++i) {
        off[i] = base;
        base += cnt[i];
    }
}

// Phase 1: the sequential scan. One block, 1024 threads (1 thread = 1 edge).
// Single workgroup -> ALL atomics at WORKGROUP scope so they execute in the
// local XCD L2 (agent scope would bypass L2 to the memory-side coherence
// point: that was 31 MB fetch / 84 MB write of HBM traffic and ~9.7 us/step).
__global__ void __launch_bounds__(1024) k_seq(const int* __restrict__ edges,
                                              const float* __restrict__ theta,
                                              float* __restrict__ X,
                                              float* __restrict__ out_kappa,
                                              const int* __restrict__ off,
                                              int* __restrict__ cur,
                                              int* __restrict__ steps,
                                              float* __restrict__ deltas) {
    const int tid = threadIdx.x;
    const float eps = sigmoid_f(theta[0]);

    // Pre-load step 0's edge triple.
    int u = edges[3 * tid + 0];
    int v = edges[3 * tid + 1];
    int s = edges[3 * tid + 2];

    for (int t = 0; t < NSTEP; ++t) {
        // Prefetch next step's edges early: their latency hides under this
        // step's gather + compute + barrier.
        int nu = 0, nv = 0, ns = 0;
        if (t + 1 < NSTEP) {
            const int nb = (t + 1) * 3 * EE + 3 * tid;
            nu = edges[nb + 0];
            nv = edges[nb + 1];
            ns = edges[nb + 2];
        }

        float xu = __hip_atomic_load(&X[u], RLX, WG);
        float xv = __hip_atomic_load(&X[v], RLX, WG);
        float diff = xu - xv;
        out_kappa[t * EE + tid] = sigmoid_f(RHO * (eps - fabsf(diff)));
        __syncthreads();   // all gathers done before any update lands
        if (s && diff != 0.0f) {
            float md = MU * diff;
            __hip_atomic_fetch_add(&X[u], -md, RLX, WG);
            __hip_atomic_fetch_add(&X[v],  md, RLX, WG);
            int pu = off[u] + __hip_atomic_fetch_add(&cur[u], 1, RLX, WG);
            steps[pu] = t; deltas[pu] = -md;
            int pv = off[v] + __hip_atomic_fetch_add(&cur[v], 1, RLX, WG);
            steps[pv] = t; deltas[pv] =  md;
        }
        __syncthreads();   // updates visible before next gather

        u = nu; v = nv; s = ns;
    }
}

// Phase 2: reconstruct rows 1..511. One thread per node walks its delta list;
// stores are fully coalesced across the block (consecutive n, same row).
__global__ void k_fill(float* __restrict__ out,
                       const int* __restrict__ off, const int* __restrict__ cur,
                       const int* __restrict__ steps,
                       const float* __restrict__ deltas) {
    int n = blockIdx.x * blockDim.x + threadIdx.x;
    if (n >= NN) return;
    float val = out[n];                   // X0[n] from row 0
    int p = off[n];
    int e = p + cur[n];
    int nxt = (p < e) ? steps[p] : 0x7fffffff;
    for (int r = 1; r < TT; ++r) {
        while (nxt < r) {                 // apply updates of step r-1
            val += deltas[p];
            ++p;
            nxt = (p < e) ? steps[p] : 0x7fffffff;
        }
        out[(size_t)r * NN + n] = val;
    }
}

extern "C" void kernel_launch(void* const* d_in, const int* in_sizes, int n_in,
                              void* d_out, int out_size, void* d_ws, size_t ws_size,
                              hipStream_t stream) {
    const float* logit = (const float*)d_in[0];
    const float* theta = (const float*)d_in[1];
    const int*   edges = (const int*)d_in[2];
    float* out = (float*)d_out;

    char* ws = (char*)d_ws;
    float* X    = (float*)ws;  ws += sizeof(float) * NN;
    int*   cnt  = (int*)ws;    ws += sizeof(int) * NN;
    int*   off  = (int*)ws;    ws += sizeof(int) * NN;
    int*   cur  = (int*)ws;    ws += sizeof(int) * NN;
    int*   stp  = (int*)ws;    ws += sizeof(int) * CAP;
    float* dels = (float*)ws;  ws += sizeof(float) * CAP;

    k_init<<<(NN + 255) / 256, 256, 0, stream>>>(logit, X, out, cnt, cur);
    k_count<<<(NSTEP * EE + 255) / 256, 256, 0, stream>>>(edges, cnt);
    k_scan<<<1, 1024, 0, stream>>>(cnt, off);
    k_seq<<<1, 1024, 0, stream>>>(edges, theta, X, out + (size_t)TT * NN,
                                  off, cur, stp, dels);
    k_fill<<<(NN + 255) / 256, 256, 0, stream>>>(out, off, cur, stp, dels);
}

// Round 3
// 2547.204 us; speedup vs baseline: 2.0512x; 2.0067x over previous
//
#include <hip/hip_runtime.h>
#include <math.h>

#define NN 100000
#define TT 512
#define EE 1024
#define NSTEP (TT - 1)              // 511
#define MU 0.05f
#define RHO 32.0f
#define CAP (NSTEP * EE * 2)        // max list entries
#define FCAP 32                     // per-node sort capacity (mean ~5.2)

#define WG __HIP_MEMORY_SCOPE_WORKGROUP
#define RLX __ATOMIC_RELAXED

__device__ __forceinline__ float sigmoid_f(float x) {
    return 1.0f / (1.0f + expf(-x));
}

// Phase 0: X = sigmoid(logit), write output row 0, zero count/cursor.
__global__ void k_init(const float* __restrict__ logit, float* __restrict__ X,
                       float* __restrict__ out, int* __restrict__ cnt,
                       int* __restrict__ cur) {
    int n = blockIdx.x * blockDim.x + threadIdx.x;
    if (n < NN) {
        float x = sigmoid_f(logit[n]);
        X[n] = x;
        out[n] = x;          // row 0 of X output
        cnt[n] = 0;
        cur[n] = 0;
    }
}

// Phase 0b: count per-node list entries (only s==1 edges modify state).
__global__ void k_count(const int* __restrict__ edges, int* __restrict__ cnt) {
    int i = blockIdx.x * blockDim.x + threadIdx.x;
    if (i < NSTEP * EE) {
        int s = edges[3 * i + 2];
        if (s) {
            atomicAdd(&cnt[edges[3 * i + 0]], 1);
            atomicAdd(&cnt[edges[3 * i + 1]], 1);
        }
    }
}

// Phase 0c: exclusive prefix sum over cnt -> off. Single block, 1024 threads.
__global__ void __launch_bounds__(1024) k_scan(const int* __restrict__ cnt,
                                               int* __restrict__ off) {
    __shared__ int sh[1024];
    int tid = threadIdx.x;
    const int seg = (NN + 1023) / 1024;   // 98
    int lo = tid * seg;
    int hi = lo + seg; if (hi > NN) hi = NN;
    int s = 0;
    for (int i = lo; i < hi; ++i) s += cnt[i];
    sh[tid] = s;
    __syncthreads();
    for (int o = 1; o < 1024; o <<= 1) {
        int v = (tid >= o) ? sh[tid - o] : 0;
        __syncthreads();
        sh[tid] += v;
        __syncthreads();
    }
    int base = sh[tid] - s;               // exclusive
    for (int i = lo; i < hi; ++i) {
        off[i] = base;
        base += cnt[i];
    }
}

// Phase 0d: parallel placement of packed keys into per-node UNORDERED lists.
// key = (t<<11) | (e<<1) | sign. Keys are unique -> k_fill's sort restores
// deterministic time order; md value is looked up by slot = key>>1.
__global__ void k_place(const int* __restrict__ edges,
                        const int* __restrict__ off, int* __restrict__ cur,
                        unsigned* __restrict__ entries) {
    int i = blockIdx.x * blockDim.x + threadIdx.x;
    if (i < NSTEP * EE) {
        int s = edges[3 * i + 2];
        if (s) {
            int u = edges[3 * i + 0];
            int v = edges[3 * i + 1];
            unsigned keyu = ((unsigned)i << 1);        // i = t*EE+e = slot
            entries[off[u] + atomicAdd(&cur[u], 1)] = keyu;       // sign 0: -md
            entries[off[v] + atomicAdd(&cur[v], 1)] = keyu | 1u;  // sign 1: +md
        }
    }
}

// Phase 1: the sequential scan. One block, 1024 threads (1 thread = 1 edge).
// Only 4 scattered wave-ops per wave per step: 2 gathers + 2 X atomics.
// kappa and md stores are fully coalesced.
__global__ void __launch_bounds__(1024) k_seq(const int* __restrict__ edges,
                                              const float* __restrict__ theta,
                                              float* __restrict__ X,
                                              float* __restrict__ out_kappa,
                                              float* __restrict__ md) {
    const int tid = threadIdx.x;
    const float eps = sigmoid_f(theta[0]);

    int u = edges[3 * tid + 0];
    int v = edges[3 * tid + 1];
    int s = edges[3 * tid + 2];

    for (int t = 0; t < NSTEP; ++t) {
        // Prefetch next step's edges; latency hides under this step.
        int nu = 0, nv = 0, ns = 0;
        if (t + 1 < NSTEP) {
            const int nb = (t + 1) * 3 * EE + 3 * tid;
            nu = edges[nb + 0];
            nv = edges[nb + 1];
            ns = edges[nb + 2];
        }

        float xu = __hip_atomic_load(&X[u], RLX, WG);
        float xv = __hip_atomic_load(&X[v], RLX, WG);
        float diff = xu - xv;
        out_kappa[t * EE + tid] = sigmoid_f(RHO * (eps - fabsf(diff)));
        bool act = (s && diff != 0.0f);
        float m = act ? MU * diff : 0.0f;
        md[t * EE + tid] = m;              // coalesced
        __syncthreads();   // all gathers done before any update lands
        if (act) {
            __hip_atomic_fetch_add(&X[u], -m, RLX, WG);
            __hip_atomic_fetch_add(&X[v],  m, RLX, WG);
        }
        __syncthreads();   // updates visible before next gather

        u = nu; v = nv; s = ns;
    }
}

// Phase 2: reconstruct rows 1..511. One thread per node: sort its keys in an
// LDS column (bank-conflict-free: lane i always hits bank i%32), then
// merge-walk the 511 rows with coalesced stores.
__global__ void __launch_bounds__(256) k_fill(float* __restrict__ out,
                                              const int* __restrict__ off,
                                              const int* __restrict__ cur,
                                              const unsigned* __restrict__ entries,
                                              const float* __restrict__ md) {
    __shared__ unsigned ent[FCAP][256];
    const int tid = threadIdx.x;
    const int n = blockIdx.x * 256 + tid;
    if (n >= NN) return;

    const int p0 = off[n];
    const int c = cur[n];
    float val = out[n];                    // X0[n] from row 0

    if (c <= FCAP) {
        // insertion sort into this thread's LDS column
        for (int k = 0; k < c; ++k) {
            unsigned key = entries[p0 + k];
            int j = k;
            while (j > 0 && ent[j - 1][tid] > key) {
                ent[j][tid] = ent[j - 1][tid];
                --j;
            }
            ent[j][tid] = key;
        }
        int p = 0;
        unsigned nxt = (c > 0) ? ent[0][tid] : 0xFFFFFFFFu;
        for (int r = 1; r < TT; ++r) {
            const unsigned lim = (unsigned)(r * EE) << 1;  // keys with t < r
            while (nxt < lim) {
                float m = md[nxt >> 1];
                val += (nxt & 1u) ? m : -m;
                ++p;
                nxt = (p < c) ? ent[p][tid] : 0xFFFFFFFFu;
            }
            out[(size_t)r * NN + n] = val;
        }
    } else {
        // rare overflow: order-free incremental rescan (t == r-1 each row)
        for (int r = 1; r < TT; ++r) {
            const unsigned lo = (unsigned)((r - 1) * EE) << 1;
            const unsigned hi = (unsigned)(r * EE) << 1;
            for (int k = 0; k < c; ++k) {
                unsigned key = entries[p0 + k];
                if (key >= lo && key < hi) {
                    float m = md[key >> 1];
                    val += (key & 1u) ? m : -m;
                }
            }
            out[(size_t)r * NN + n] = val;
        }
    }
}

extern "C" void kernel_launch(void* const* d_in, const int* in_sizes, int n_in,
                              void* d_out, int out_size, void* d_ws, size_t ws_size,
                              hipStream_t stream) {
    const float* logit = (const float*)d_in[0];
    const float* theta = (const float*)d_in[1];
    const int*   edges = (const int*)d_in[2];
    float* out = (float*)d_out;

    char* ws = (char*)d_ws;
    float*    X    = (float*)ws;     ws += sizeof(float) * NN;
    int*      cnt  = (int*)ws;       ws += sizeof(int) * NN;
    int*      off  = (int*)ws;       ws += sizeof(int) * NN;
    int*      cur  = (int*)ws;       ws += sizeof(int) * NN;
    unsigned* ent  = (unsigned*)ws;  ws += sizeof(unsigned) * CAP;
    float*    md   = (float*)ws;     ws += sizeof(float) * (NSTEP * EE);

    k_init<<<(NN + 255) / 256, 256, 0, stream>>>(logit, X, out, cnt, cur);
    k_count<<<(NSTEP * EE + 255) / 256, 256, 0, stream>>>(edges, cnt);
    k_scan<<<1, 1024, 0, stream>>>(cnt, off);
    k_place<<<(NSTEP * EE + 255) / 256, 256, 0, stream>>>(edges, off, cur, ent);
    k_seq<<<1, 1024, 0, stream>>>(edges, theta, X, out + (size_t)TT * NN, md);
    k_fill<<<(NN + 255) / 256, 256, 0, stream>>>(out, off, cur, ent, md);
}

// Round 6
// 461.377 us; speedup vs baseline: 11.3244x; 5.5209x over previous
//
#include <hip/hip_runtime.h>
#include <math.h>

#define NN 100000
#define TT 512
#define EE 1024
#define NSTEP (TT - 1)              // 511
#define NE (NSTEP * EE)             // 523,264 edges
#define NCHUNK (NE / 256)           // 2044 chunks of 256 edges (chunk ⊂ one step)
#define FLOWG 512                   // cooperative grid: 2 blocks/CU, huge slack
#define MU 0.05f
#define RHO 32.0f
#define CAP (NE * 2)                // 1,046,528 max list entries
#define NOTREADY 0xFFFFFFFFu        // X values finite positive: never this bit pattern

#define SYS __HIP_MEMORY_SCOPE_SYSTEM
#define WGS __HIP_MEMORY_SCOPE_WORKGROUP
#define RLX __ATOMIC_RELAXED

__device__ __forceinline__ float sigmoid_f(float x) {
    return 1.0f / (1.0f + expf(-x));
}

__device__ __forceinline__ unsigned try_val(unsigned* pub, int p) {
    return __hip_atomic_load(&pub[p], RLX, SYS);
}
__device__ __forceinline__ void publish(unsigned* pub, int p, float v) {
    __hip_atomic_store(&pub[p], __float_as_uint(v), RLX, SYS);
}

__device__ __forceinline__ int lower_bound(const unsigned* __restrict__ a,
                                           int lo, int hi, unsigned key) {
    while (lo < hi) {
        int mid = (lo + hi) >> 1;
        if (a[mid] < key) lo = mid + 1; else hi = mid;
    }
    return lo;
}

// Phase 0: X0 = sigmoid(logit), write output row 0, zero count/cursor.
__global__ void k_init(const float* __restrict__ logit, float* __restrict__ X0f,
                       float* __restrict__ out, int* __restrict__ cnt,
                       int* __restrict__ cur) {
    int n = blockIdx.x * blockDim.x + threadIdx.x;
    if (n < NN) {
        float x = sigmoid_f(logit[n]);
        X0f[n] = x;
        out[n] = x;          // row 0 of X output
        cnt[n] = 0;
        cur[n] = 0;
    }
}

// Phase 0a: reset publication slots (every call: graph replays must not see
// the previous run's published values).
__global__ void k_pubinit(unsigned* __restrict__ pub) {
    int i = blockIdx.x * blockDim.x + threadIdx.x;
    if (i < CAP) pub[i] = NOTREADY;
}

// Phase 0b: count per-node list entries (only s==1 edges modify state).
__global__ void k_count(const int* __restrict__ edges, int* __restrict__ cnt) {
    int i = blockIdx.x * blockDim.x + threadIdx.x;
    if (i < NE) {
        int s = edges[3 * i + 2];
        if (s) {
            atomicAdd(&cnt[edges[3 * i + 0]], 1);
            atomicAdd(&cnt[edges[3 * i + 1]], 1);
        }
    }
}

// Phase 0c: exclusive prefix sum over cnt -> off. Single block, 1024 threads.
__global__ void __launch_bounds__(1024) k_scan(const int* __restrict__ cnt,
                                               int* __restrict__ off) {
    __shared__ int sh[1024];
    int tid = threadIdx.x;
    const int seg = (NN + 1023) / 1024;   // 98
    int lo = tid * seg;
    int hi = lo + seg; if (hi > NN) hi = NN;
    int s = 0;
    for (int i = lo; i < hi; ++i) s += cnt[i];
    sh[tid] = s;
    __syncthreads();
    for (int o = 1; o < 1024; o <<= 1) {
        int v = (tid >= o) ? sh[tid - o] : 0;
        __syncthreads();
        sh[tid] += v;
        __syncthreads();
    }
    int base = sh[tid] - s;               // exclusive
    for (int i = lo; i < hi; ++i) {
        off[i] = base;
        base += cnt[i];
    }
}

// Phase 0d: place packed keys (t*EE+e)<<1 | side into per-node unordered lists.
__global__ void k_place(const int* __restrict__ edges,
                        const int* __restrict__ off, int* __restrict__ cur,
                        unsigned* __restrict__ ent) {
    int i = blockIdx.x * blockDim.x + threadIdx.x;
    if (i < NE) {
        int s = edges[3 * i + 2];
        if (s) {
            int u = edges[3 * i + 0];
            int v = edges[3 * i + 1];
            unsigned key = ((unsigned)i) << 1;
            ent[off[u] + atomicAdd(&cur[u], 1)] = key;        // side 0: -md
            ent[off[v] + atomicAdd(&cur[v], 1)] = key | 1u;   // side 1: +md
        }
    }
}

// Phase 0e: sort each node's list (keys unique -> deterministic). c ~ 5 avg.
__global__ void k_sort(const int* __restrict__ off, const int* __restrict__ cur,
                       unsigned* __restrict__ ent) {
    int n = blockIdx.x * blockDim.x + threadIdx.x;
    if (n >= NN) return;
    int lo = off[n], c = cur[n];
    for (int k = 1; k < c; ++k) {
        unsigned key = ent[lo + k];
        int j = k;
        while (j > 0 && ent[lo + j - 1] > key) {
            ent[lo + j] = ent[lo + j - 1];
            --j;
        }
        ent[lo + j] = key;
    }
}

// Phase 1: dataflow evaluation. One thread per edge; chunks processed in
// increasing global order. DEADLOCK-SAFE SPIN: one flattened poll loop with a
// per-lane state machine — a lane that becomes ready PUBLISHES INSIDE the
// loop body, so same-wave dependents see it on their next poll iteration
// (nested wait loops would deadlock: the publisher is masked off until the
// waiter's loop reconverges). Launched cooperatively -> all blocks resident.
__global__ void __launch_bounds__(256, 2)
k_flow(const int* __restrict__ edges, const float* __restrict__ theta,
       const float* __restrict__ X0f, const int* __restrict__ off,
       const int* __restrict__ cur, const unsigned* __restrict__ ent,
       unsigned* __restrict__ pub, float* __restrict__ out_kappa) {
    const float eps = sigmoid_f(theta[0]);
    for (int c = blockIdx.x; c < NCHUNK; c += gridDim.x) {
        const int i = (c << 8) + threadIdx.x;
        const int t = i >> 10;                     // i / EE
        const int u = edges[3 * i + 0];
        const int v = edges[3 * i + 1];
        const int s = edges[3 * i + 2];

        const unsigned stepkey = ((unsigned)t) << 11;  // first key of step t

        const int lu = off[u], hu = lu + cur[u];
        const int qu = lower_bound(ent, lu, hu, stepkey);
        const int lv = off[v], hv = lv + cur[v];
        const int qv = lower_bound(ent, lv, hv, stepkey);

        // Locate own entries (s==1 only): linear scan within the step group.
        int mu_ = -1, mv_ = -1;
        if (s) {
            const unsigned ku = ((unsigned)i) << 1;
            mu_ = qu; while (ent[mu_] != ku) ++mu_;
            const unsigned kv = ku | 1u;
            mv_ = qv; while (ent[mv_] != kv) ++mv_;
        }

        // State machine flags.
        bool have_xu = (qu == lu);
        bool have_xv = (qv == lv);
        float xu = have_xu ? X0f[u] : 0.0f;
        float xv = have_xv ? X0f[v] : 0.0f;
        bool kap_done = false;
        bool pu_done = (s == 0);
        bool pv_done = (s == 0);
        float m = 0.0f;

        while (!(kap_done && pu_done && pv_done)) {
            if (!have_xu) {
                unsigned w = try_val(pub, qu - 1);
                if (w != NOTREADY) { xu = __uint_as_float(w); have_xu = true; }
            }
            if (!have_xv) {
                unsigned w = try_val(pub, qv - 1);
                if (w != NOTREADY) { xv = __uint_as_float(w); have_xv = true; }
            }
            if (have_xu && have_xv && !kap_done) {
                float diff = xu - xv;
                m = MU * diff;
                out_kappa[i] = sigmoid_f(RHO * (eps - fabsf(diff)));
                kap_done = true;
            }
            if (kap_done && !pu_done) {
                bool rdy; float baseu = xu;
                if (mu_ == qu) rdy = true;
                else {
                    unsigned w = try_val(pub, mu_ - 1);
                    rdy = (w != NOTREADY);
                    if (rdy) baseu = __uint_as_float(w);
                }
                if (rdy) { publish(pub, mu_, baseu - m); pu_done = true; }
            }
            if (kap_done && !pv_done) {
                bool rdy; float basev = xv;
                if (mv_ == qv) rdy = true;
                else {
                    unsigned w = try_val(pub, mv_ - 1);
                    rdy = (w != NOTREADY);
                    if (rdy) basev = __uint_as_float(w);
                }
                if (rdy) { publish(pub, mv_, basev + m); pv_done = true; }
            }
            if (!(kap_done && pu_done && pv_done)) __builtin_amdgcn_s_sleep(1);
        }
    }
}

// Phase 2 (main): reconstruct rows 1..511 from published running values.
__global__ void k_fill_pub(float* __restrict__ out,
                           const int* __restrict__ off,
                           const int* __restrict__ cur,
                           const unsigned* __restrict__ ent,
                           const unsigned* __restrict__ pub) {
    int n = blockIdx.x * blockDim.x + threadIdx.x;
    if (n >= NN) return;
    float val = out[n];                   // X0[n] from row 0
    int p = off[n];
    const int e2 = p + cur[n];
    unsigned nxt = (p < e2) ? ent[p] : 0xFFFFFFFFu;
    for (int r = 1; r < TT; ++r) {
        const unsigned lim = ((unsigned)r) << 11;   // keys with t < r
        while (nxt < lim) {
            val = __uint_as_float(pub[p]);          // running value after entry
            ++p;
            nxt = (p < e2) ? ent[p] : 0xFFFFFFFFu;
        }
        out[(size_t)r * NN + n] = val;
    }
}

// ---------- fallback path (proven R3, 2.26 ms): sequential scan ----------
__global__ void __launch_bounds__(1024) k_seq(const int* __restrict__ edges,
                                              const float* __restrict__ theta,
                                              float* __restrict__ X,
                                              float* __restrict__ out_kappa,
                                              float* __restrict__ md) {
    const int tid = threadIdx.x;
    const float eps = sigmoid_f(theta[0]);
    int u = edges[3 * tid + 0];
    int v = edges[3 * tid + 1];
    int s = edges[3 * tid + 2];
    for (int t = 0; t < NSTEP; ++t) {
        int nu = 0, nv = 0, ns = 0;
        if (t + 1 < NSTEP) {
            const int nb = (t + 1) * 3 * EE + 3 * tid;
            nu = edges[nb + 0]; nv = edges[nb + 1]; ns = edges[nb + 2];
        }
        float xu = __hip_atomic_load(&X[u], RLX, WGS);
        float xv = __hip_atomic_load(&X[v], RLX, WGS);
        float diff = xu - xv;
        out_kappa[t * EE + tid] = sigmoid_f(RHO * (eps - fabsf(diff)));
        bool act = (s && diff != 0.0f);
        float m = act ? MU * diff : 0.0f;
        md[t * EE + tid] = m;
        __syncthreads();
        if (act) {
            __hip_atomic_fetch_add(&X[u], -m, RLX, WGS);
            __hip_atomic_fetch_add(&X[v],  m, RLX, WGS);
        }
        __syncthreads();
        u = nu; v = nv; s = ns;
    }
}

__global__ void k_fill_md(float* __restrict__ out,
                          const int* __restrict__ off, const int* __restrict__ cur,
                          const unsigned* __restrict__ ent,
                          const float* __restrict__ md) {
    int n = blockIdx.x * blockDim.x + threadIdx.x;
    if (n >= NN) return;
    float val = out[n];
    int p = off[n];
    const int e2 = p + cur[n];
    unsigned nxt = (p < e2) ? ent[p] : 0xFFFFFFFFu;
    for (int r = 1; r < TT; ++r) {
        const unsigned lim = ((unsigned)r) << 11;
        while (nxt < lim) {
            float m = md[nxt >> 1];
            val += (nxt & 1u) ? m : -m;
            ++p;
            nxt = (p < e2) ? ent[p] : 0xFFFFFFFFu;
        }
        out[(size_t)r * NN + n] = val;
    }
}
// ---------------------------------------------------------------------------

extern "C" void kernel_launch(void* const* d_in, const int* in_sizes, int n_in,
                              void* d_out, int out_size, void* d_ws, size_t ws_size,
                              hipStream_t stream) {
    const float* logit = (const float*)d_in[0];
    const float* theta = (const float*)d_in[1];
    const int*   edges = (const int*)d_in[2];
    float* out = (float*)d_out;
    float* kap = out + (size_t)TT * NN;

    char* ws = (char*)d_ws;
    float*    X0f = (float*)ws;     ws += sizeof(float) * NN;
    int*      cnt = (int*)ws;       ws += sizeof(int) * NN;
    int*      off = (int*)ws;       ws += sizeof(int) * NN;
    int*      cur = (int*)ws;       ws += sizeof(int) * NN;
    unsigned* ent = (unsigned*)ws;  ws += sizeof(unsigned) * CAP;
    // main path uses pub (CAP u32); fallback uses md (NE f32). They overlap.
    unsigned* pub = (unsigned*)ws;
    float*    md  = (float*)ws;

    const size_t need_main = (size_t)(4 * NN) * 4 + (size_t)CAP * 4 * 2;
    const bool main_path = ws_size >= need_main;

    k_init <<<(NN + 255) / 256, 256, 0, stream>>>(logit, X0f, out, cnt, cur);
    k_count<<<(NE + 255) / 256, 256, 0, stream>>>(edges, cnt);
    k_scan <<<1, 1024, 0, stream>>>(cnt, off);
    k_place<<<(NE + 255) / 256, 256, 0, stream>>>(edges, off, cur, ent);
    k_sort <<<(NN + 255) / 256, 256, 0, stream>>>(off, cur, ent);

    bool flow_ok = false;
    if (main_path) {
        k_pubinit<<<(CAP + 255) / 256, 256, 0, stream>>>(pub);
        const int* a_edges = edges; const float* a_theta = theta;
        const float* a_x0 = X0f; const int* a_off = off; const int* a_cur = cur;
        const unsigned* a_ent = ent; unsigned* a_pub = pub; float* a_kap = kap;
        void* args[] = { &a_edges, &a_theta, &a_x0, &a_off, &a_cur,
                         &a_ent, &a_pub, &a_kap };
        hipError_t e = hipLaunchCooperativeKernel((const void*)k_flow,
                                                  dim3(FLOWG), dim3(256),
                                                  args, 0, stream);
        if (e == hipSuccess) {
            flow_ok = true;
            k_fill_pub<<<(NN + 255) / 256, 256, 0, stream>>>(out, off, cur,
                                                             ent, pub);
        } else {
            (void)hipGetLastError();
        }
    }
    if (!flow_ok) {
        // Proven sequential path (R3): single-block scan + delta fill.
        k_seq<<<1, 1024, 0, stream>>>(edges, theta, X0f, kap, md);
        k_fill_md<<<(NN + 255) / 256, 256, 0, stream>>>(out, off, cur, ent, md);
    }
}

// Round 7
// 311.503 us; speedup vs baseline: 16.7729x; 1.4811x over previous
//
#include <hip/hip_runtime.h>
#include <math.h>

#define NN 100000
#define TT 512
#define EE 1024
#define NSTEP (TT - 1)              // 511
#define NE (NSTEP * EE)             // 523,264 edges
#define NCHUNK (NE / 256)           // 2044 chunks of 256 edges (chunk ⊂ one step)
#define FLOWG 512                   // cooperative grid: 2 blocks/CU, huge slack
#define MU 0.05f
#define RHO 32.0f
#define CAP (NE * 2)                // 1,046,528 max list entries
#define NOTREADY 0xFFFFFFFFu        // X values finite positive: never this bit pattern
#define SCAN_BLK 1024               // elements per scan block
#define SCAN_NB ((NN + SCAN_BLK - 1) / SCAN_BLK)   // 98

#define SYS __HIP_MEMORY_SCOPE_SYSTEM
#define WGS __HIP_MEMORY_SCOPE_WORKGROUP
#define RLX __ATOMIC_RELAXED

__device__ __forceinline__ float sigmoid_f(float x) {
    return 1.0f / (1.0f + expf(-x));
}

__device__ __forceinline__ unsigned try_val(unsigned* pub, int p) {
    return __hip_atomic_load(&pub[p], RLX, SYS);
}
__device__ __forceinline__ void publish(unsigned* pub, int p, float v) {
    __hip_atomic_store(&pub[p], __float_as_uint(v), RLX, SYS);
}

__device__ __forceinline__ int lower_bound(const unsigned* __restrict__ a,
                                           int lo, int hi, unsigned key) {
    while (lo < hi) {
        int mid = (lo + hi) >> 1;
        if (a[mid] < key) lo = mid + 1; else hi = mid;
    }
    return lo;
}

// Phase 0: X0 = sigmoid(logit), write output row 0, zero count/cursor.
__global__ void k_init(const float* __restrict__ logit, float* __restrict__ X0f,
                       float* __restrict__ out, int* __restrict__ cnt,
                       int* __restrict__ cur) {
    int n = blockIdx.x * blockDim.x + threadIdx.x;
    if (n < NN) {
        float x = sigmoid_f(logit[n]);
        X0f[n] = x;
        out[n] = x;          // row 0 of X output
        cnt[n] = 0;
        cur[n] = 0;
    }
}

// Phase 0b: count per-node list entries + reset publication slots (graph
// replays must not see the previous run's published values).
__global__ void k_count(const int* __restrict__ edges, int* __restrict__ cnt,
                        unsigned* __restrict__ pub) {
    int i = blockIdx.x * blockDim.x + threadIdx.x;
    if (i < NE) {
        pub[2 * i]     = NOTREADY;
        pub[2 * i + 1] = NOTREADY;
        int s = edges[3 * i + 2];
        if (s) {
            atomicAdd(&cnt[edges[3 * i + 0]], 1);
            atomicAdd(&cnt[edges[3 * i + 1]], 1);
        }
    }
}

// Phase 0c: 3-phase multi-block exclusive scan over cnt -> off.
// A: per-block (1024 elems, 256 thr x int4) reduce -> bsum[b].
__global__ void __launch_bounds__(256) k_scanA(const int* __restrict__ cnt,
                                               int* __restrict__ bsum) {
    __shared__ int sh[256];
    const int t = threadIdx.x;
    const int base = blockIdx.x * SCAN_BLK + t * 4;
    int s = 0;
    if (base + 3 < NN) {
        const int4 v = *(const int4*)(cnt + base);
        s = v.x + v.y + v.z + v.w;
    } else {
        for (int k = 0; k < 4; ++k) if (base + k < NN) s += cnt[base + k];
    }
    sh[t] = s;
    __syncthreads();
    for (int o = 128; o > 0; o >>= 1) {
        if (t < o) sh[t] += sh[t + o];
        __syncthreads();
    }
    if (t == 0) bsum[blockIdx.x] = sh[0];
}

// B: one small block turns bsum into its exclusive scan (98 entries).
__global__ void __launch_bounds__(128) k_scanB(int* __restrict__ bsum) {
    __shared__ int sh[128];
    const int t = threadIdx.x;
    int v = (t < SCAN_NB) ? bsum[t] : 0;
    sh[t] = v;
    __syncthreads();
    for (int o = 1; o < 128; o <<= 1) {
        int x = (t >= o) ? sh[t - o] : 0;
        __syncthreads();
        sh[t] += x;
        __syncthreads();
    }
    if (t < SCAN_NB) bsum[t] = sh[t] - v;   // exclusive
}

// C: per-block local exclusive scan + block offset, int4 stores.
__global__ void __launch_bounds__(256) k_scanC(const int* __restrict__ cnt,
                                               const int* __restrict__ bsum,
                                               int* __restrict__ off) {
    __shared__ int sh[256];
    const int t = threadIdx.x;
    const int base = blockIdx.x * SCAN_BLK + t * 4;
    int a0 = 0, a1 = 0, a2 = 0, a3 = 0;
    if (base + 3 < NN) {
        const int4 v = *(const int4*)(cnt + base);
        a0 = v.x; a1 = v.y; a2 = v.z; a3 = v.w;
    } else {
        if (base + 0 < NN) a0 = cnt[base + 0];
        if (base + 1 < NN) a1 = cnt[base + 1];
        if (base + 2 < NN) a2 = cnt[base + 2];
    }
    const int s = a0 + a1 + a2 + a3;
    sh[t] = s;
    __syncthreads();
    for (int o = 1; o < 256; o <<= 1) {
        int x = (t >= o) ? sh[t - o] : 0;
        __syncthreads();
        sh[t] += x;
        __syncthreads();
    }
    int ex = sh[t] - s + bsum[blockIdx.x];
    if (base + 3 < NN) {
        int4 w; w.x = ex; w.y = ex + a0; w.z = ex + a0 + a1; w.w = ex + a0 + a1 + a2;
        *(int4*)(off + base) = w;
    } else {
        if (base + 0 < NN) off[base + 0] = ex;
        if (base + 1 < NN) off[base + 1] = ex + a0;
        if (base + 2 < NN) off[base + 2] = ex + a0 + a1;
    }
}

// Phase 0d: place packed keys (t*EE+e)<<1 | side into per-node unordered lists.
__global__ void k_place(const int* __restrict__ edges,
                        const int* __restrict__ off, int* __restrict__ cur,
                        unsigned* __restrict__ ent) {
    int i = blockIdx.x * blockDim.x + threadIdx.x;
    if (i < NE) {
        int s = edges[3 * i + 2];
        if (s) {
            int u = edges[3 * i + 0];
            int v = edges[3 * i + 1];
            unsigned key = ((unsigned)i) << 1;
            ent[off[u] + atomicAdd(&cur[u], 1)] = key;        // side 0: -md
            ent[off[v] + atomicAdd(&cur[v], 1)] = key | 1u;   // side 1: +md
        }
    }
}

// Phase 0e: sort each node's list (keys unique -> deterministic). c ~ 5 avg.
__global__ void k_sort(const int* __restrict__ off, const int* __restrict__ cur,
                       unsigned* __restrict__ ent) {
    int n = blockIdx.x * blockDim.x + threadIdx.x;
    if (n >= NN) return;
    int lo = off[n], c = cur[n];
    for (int k = 1; k < c; ++k) {
        unsigned key = ent[lo + k];
        int j = k;
        while (j > 0 && ent[lo + j - 1] > key) {
            ent[lo + j] = ent[lo + j - 1];
            --j;
        }
        ent[lo + j] = key;
    }
}

// Phase 1: dataflow evaluation. One thread per edge; chunks processed in
// increasing global order. DEADLOCK-SAFE SPIN: one flattened poll loop with a
// per-lane state machine — a lane that becomes ready PUBLISHES INSIDE the
// loop body, so same-wave dependents see it on their next poll iteration.
// Launched cooperatively -> all blocks resident.
__global__ void __launch_bounds__(256, 2)
k_flow(const int* __restrict__ edges, const float* __restrict__ theta,
       const float* __restrict__ X0f, const int* __restrict__ off,
       const int* __restrict__ cur, const unsigned* __restrict__ ent,
       unsigned* __restrict__ pub, float* __restrict__ out_kappa) {
    const float eps = sigmoid_f(theta[0]);
    for (int c = blockIdx.x; c < NCHUNK; c += gridDim.x) {
        const int i = (c << 8) + threadIdx.x;
        const int t = i >> 10;                     // i / EE
        const int u = edges[3 * i + 0];
        const int v = edges[3 * i + 1];
        const int s = edges[3 * i + 2];

        const unsigned stepkey = ((unsigned)t) << 11;  // first key of step t

        const int lu = off[u], hu = lu + cur[u];
        const int qu = lower_bound(ent, lu, hu, stepkey);
        const int lv = off[v], hv = lv + cur[v];
        const int qv = lower_bound(ent, lv, hv, stepkey);

        // Locate own entries (s==1 only): linear scan within the step group.
        int mu_ = -1, mv_ = -1;
        if (s) {
            const unsigned ku = ((unsigned)i) << 1;
            mu_ = qu; while (ent[mu_] != ku) ++mu_;
            const unsigned kv = ku | 1u;
            mv_ = qv; while (ent[mv_] != kv) ++mv_;
        }

        // State machine flags.
        bool have_xu = (qu == lu);
        bool have_xv = (qv == lv);
        float xu = have_xu ? X0f[u] : 0.0f;
        float xv = have_xv ? X0f[v] : 0.0f;
        bool kap_done = false;
        bool pu_done = (s == 0);
        bool pv_done = (s == 0);
        float m = 0.0f;

        while (!(kap_done && pu_done && pv_done)) {
            if (!have_xu) {
                unsigned w = try_val(pub, qu - 1);
                if (w != NOTREADY) { xu = __uint_as_float(w); have_xu = true; }
            }
            if (!have_xv) {
                unsigned w = try_val(pub, qv - 1);
                if (w != NOTREADY) { xv = __uint_as_float(w); have_xv = true; }
            }
            if (have_xu && have_xv && !kap_done) {
                float diff = xu - xv;
                m = MU * diff;
                out_kappa[i] = sigmoid_f(RHO * (eps - fabsf(diff)));
                kap_done = true;
            }
            if (kap_done && !pu_done) {
                bool rdy; float baseu = xu;
                if (mu_ == qu) rdy = true;
                else {
                    unsigned w = try_val(pub, mu_ - 1);
                    rdy = (w != NOTREADY);
                    if (rdy) baseu = __uint_as_float(w);
                }
                if (rdy) { publish(pub, mu_, baseu - m); pu_done = true; }
            }
            if (kap_done && !pv_done) {
                bool rdy; float basev = xv;
                if (mv_ == qv) rdy = true;
                else {
                    unsigned w = try_val(pub, mv_ - 1);
                    rdy = (w != NOTREADY);
                    if (rdy) basev = __uint_as_float(w);
                }
                if (rdy) { publish(pub, mv_, basev + m); pv_done = true; }
            }
            if (!(kap_done && pu_done && pv_done)) __builtin_amdgcn_s_sleep(1);
        }
    }
}

// Phase 2 (main): reconstruct rows 1..511 from published running values.
__global__ void k_fill_pub(float* __restrict__ out,
                           const int* __restrict__ off,
                           const int* __restrict__ cur,
                           const unsigned* __restrict__ ent,
                           const unsigned* __restrict__ pub) {
    int n = blockIdx.x * blockDim.x + threadIdx.x;
    if (n >= NN) return;
    float val = out[n];                   // X0[n] from row 0
    int p = off[n];
    const int e2 = p + cur[n];
    unsigned nxt = (p < e2) ? ent[p] : 0xFFFFFFFFu;
    for (int r = 1; r < TT; ++r) {
        const unsigned lim = ((unsigned)r) << 11;   // keys with t < r
        while (nxt < lim) {
            val = __uint_as_float(pub[p]);          // running value after entry
            ++p;
            nxt = (p < e2) ? ent[p] : 0xFFFFFFFFu;
        }
        out[(size_t)r * NN + n] = val;
    }
}

// ---------- fallback path (proven R3, 2.26 ms): sequential scan ----------
__global__ void __launch_bounds__(1024) k_seq(const int* __restrict__ edges,
                                              const float* __restrict__ theta,
                                              float* __restrict__ X,
                                              float* __restrict__ out_kappa,
                                              float* __restrict__ md) {
    const int tid = threadIdx.x;
    const float eps = sigmoid_f(theta[0]);
    int u = edges[3 * tid + 0];
    int v = edges[3 * tid + 1];
    int s = edges[3 * tid + 2];
    for (int t = 0; t < NSTEP; ++t) {
        int nu = 0, nv = 0, ns = 0;
        if (t + 1 < NSTEP) {
            const int nb = (t + 1) * 3 * EE + 3 * tid;
            nu = edges[nb + 0]; nv = edges[nb + 1]; ns = edges[nb + 2];
        }
        float xu = __hip_atomic_load(&X[u], RLX, WGS);
        float xv = __hip_atomic_load(&X[v], RLX, WGS);
        float diff = xu - xv;
        out_kappa[t * EE + tid] = sigmoid_f(RHO * (eps - fabsf(diff)));
        bool act = (s && diff != 0.0f);
        float m = act ? MU * diff : 0.0f;
        md[t * EE + tid] = m;
        __syncthreads();
        if (act) {
            __hip_atomic_fetch_add(&X[u], -m, RLX, WGS);
            __hip_atomic_fetch_add(&X[v],  m, RLX, WGS);
        }
        __syncthreads();
        u = nu; v = nv; s = ns;
    }
}

__global__ void k_fill_md(float* __restrict__ out,
                          const int* __restrict__ off, const int* __restrict__ cur,
                          const unsigned* __restrict__ ent,
                          const float* __restrict__ md) {
    int n = blockIdx.x * blockDim.x + threadIdx.x;
    if (n >= NN) return;
    float val = out[n];
    int p = off[n];
    const int e2 = p + cur[n];
    unsigned nxt = (p < e2) ? ent[p] : 0xFFFFFFFFu;
    for (int r = 1; r < TT; ++r) {
        const unsigned lim = ((unsigned)r) << 11;
        while (nxt < lim) {
            float m = md[nxt >> 1];
            val += (nxt & 1u) ? m : -m;
            ++p;
            nxt = (p < e2) ? ent[p] : 0xFFFFFFFFu;
        }
        out[(size_t)r * NN + n] = val;
    }
}
// ---------------------------------------------------------------------------

extern "C" void kernel_launch(void* const* d_in, const int* in_sizes, int n_in,
                              void* d_out, int out_size, void* d_ws, size_t ws_size,
                              hipStream_t stream) {
    const float* logit = (const float*)d_in[0];
    const float* theta = (const float*)d_in[1];
    const int*   edges = (const int*)d_in[2];
    float* out = (float*)d_out;
    float* kap = out + (size_t)TT * NN;

    char* ws = (char*)d_ws;
    float*    X0f  = (float*)ws;    ws += sizeof(float) * NN;
    int*      cnt  = (int*)ws;      ws += sizeof(int) * NN;
    int*      off  = (int*)ws;      ws += sizeof(int) * NN;
    int*      cur  = (int*)ws;      ws += sizeof(int) * NN;
    int*      bsum = (int*)ws;      ws += sizeof(int) * ((SCAN_NB + 3) & ~3);
    unsigned* ent  = (unsigned*)ws; ws += sizeof(unsigned) * CAP;
    // main path uses pub (CAP u32); fallback uses md (NE f32). They overlap.
    unsigned* pub = (unsigned*)ws;
    float*    md  = (float*)ws;

    const size_t need_main = (size_t)(4 * NN + SCAN_NB + 3) * 4
                           + (size_t)CAP * 4 * 2;
    const bool main_path = ws_size >= need_main;

    k_init <<<(NN + 255) / 256, 256, 0, stream>>>(logit, X0f, out, cnt, cur);
    k_count<<<(NE + 255) / 256, 256, 0, stream>>>(edges, cnt, pub);
    k_scanA<<<SCAN_NB, 256, 0, stream>>>(cnt, bsum);
    k_scanB<<<1, 128, 0, stream>>>(bsum);
    k_scanC<<<SCAN_NB, 256, 0, stream>>>(cnt, bsum, off);
    k_place<<<(NE + 255) / 256, 256, 0, stream>>>(edges, off, cur, ent);
    k_sort <<<(NN + 255) / 256, 256, 0, stream>>>(off, cur, ent);

    bool flow_ok = false;
    if (main_path) {
        const int* a_edges = edges; const float* a_theta = theta;
        const float* a_x0 = X0f; const int* a_off = off; const int* a_cur = cur;
        const unsigned* a_ent = ent; unsigned* a_pub = pub; float* a_kap = kap;
        void* args[] = { &a_edges, &a_theta, &a_x0, &a_off, &a_cur,
                         &a_ent, &a_pub, &a_kap };
        hipError_t e = hipLaunchCooperativeKernel((const void*)k_flow,
                                                  dim3(FLOWG), dim3(256),
                                                  args, 0, stream);
        if (e == hipSuccess) {
            flow_ok = true;
            k_fill_pub<<<(NN + 255) / 256, 256, 0, stream>>>(out, off, cur,
                                                             ent, pub);
        } else {
            (void)hipGetLastError();
        }
    }
    if (!flow_ok) {
        // Proven sequential path (R3): single-block scan + delta fill.
        k_seq<<<1, 1024, 0, stream>>>(edges, theta, X0f, kap, md);
        k_fill_md<<<(NN + 255) / 256, 256, 0, stream>>>(out, off, cur, ent, md);
    }
}

// Round 8
// 254.225 us; speedup vs baseline: 20.5519x; 1.2253x over previous
//
#include <hip/hip_runtime.h>
#include <math.h>

#define NN 100000
#define TT 512
#define EE 1024
#define NSTEP (TT - 1)              // 511
#define NE (NSTEP * EE)             // 523,264 edges
#define NCHUNK (NE / 256)           // 2044 chunks of 256 edges (chunk ⊂ one step)
#define FLOWG 512                   // cooperative grid: 2 blocks/CU, huge slack
#define MU 0.05f
#define RHO 32.0f
#define CAP (NE * 2)                // 1,046,528 max list entries
#define NOTREADY 0xFFFFFFFFu        // X values finite positive: never this bit pattern
#define SCAN_BLK 1024               // elements per scan block
#define SCAN_NB ((NN + SCAN_BLK - 1) / SCAN_BLK)   // 98
#define RB 32                       // rows per fill chunk
#define NRC (TT / RB)               // 16 row chunks
#define FILL_BX ((NN / 4 + 255) / 256)             // 98 blocks in node dim

#define SYS __HIP_MEMORY_SCOPE_SYSTEM
#define WGS __HIP_MEMORY_SCOPE_WORKGROUP
#define RLX __ATOMIC_RELAXED

__device__ __forceinline__ float sigmoid_f(float x) {
    return 1.0f / (1.0f + expf(-x));
}

__device__ __forceinline__ unsigned try_val(unsigned* pub, int p) {
    return __hip_atomic_load(&pub[p], RLX, SYS);
}
__device__ __forceinline__ void publish(unsigned* pub, int p, float v) {
    __hip_atomic_store(&pub[p], __float_as_uint(v), RLX, SYS);
}

__device__ __forceinline__ int lower_bound(const unsigned* __restrict__ a,
                                           int lo, int hi, unsigned key) {
    while (lo < hi) {
        int mid = (lo + hi) >> 1;
        if (a[mid] < key) lo = mid + 1; else hi = mid;
    }
    return lo;
}

// Phase 0: X0 = sigmoid(logit), write output row 0, zero count/cursor.
__global__ void k_init(const float* __restrict__ logit, float* __restrict__ X0f,
                       float* __restrict__ out, int* __restrict__ cnt,
                       int* __restrict__ cur) {
    int n = blockIdx.x * blockDim.x + threadIdx.x;
    if (n < NN) {
        float x = sigmoid_f(logit[n]);
        X0f[n] = x;
        out[n] = x;          // row 0 of X output
        cnt[n] = 0;
        cur[n] = 0;
    }
}

// Phase 0b: count per-node list entries + reset publication slots (graph
// replays must not see the previous run's published values).
__global__ void k_count(const int* __restrict__ edges, int* __restrict__ cnt,
                        unsigned* __restrict__ pub) {
    int i = blockIdx.x * blockDim.x + threadIdx.x;
    if (i < NE) {
        pub[2 * i]     = NOTREADY;
        pub[2 * i + 1] = NOTREADY;
        int s = edges[3 * i + 2];
        if (s) {
            atomicAdd(&cnt[edges[3 * i + 0]], 1);
            atomicAdd(&cnt[edges[3 * i + 1]], 1);
        }
    }
}

// Phase 0c: 3-phase multi-block exclusive scan over cnt -> off.
// A: per-block (1024 elems, 256 thr x int4) reduce -> bsum[b].
__global__ void __launch_bounds__(256) k_scanA(const int* __restrict__ cnt,
                                               int* __restrict__ bsum) {
    __shared__ int sh[256];
    const int t = threadIdx.x;
    const int base = blockIdx.x * SCAN_BLK + t * 4;
    int s = 0;
    if (base + 3 < NN) {
        const int4 v = *(const int4*)(cnt + base);
        s = v.x + v.y + v.z + v.w;
    } else {
        for (int k = 0; k < 4; ++k) if (base + k < NN) s += cnt[base + k];
    }
    sh[t] = s;
    __syncthreads();
    for (int o = 128; o > 0; o >>= 1) {
        if (t < o) sh[t] += sh[t + o];
        __syncthreads();
    }
    if (t == 0) bsum[blockIdx.x] = sh[0];
}

// B: one small block turns bsum into its exclusive scan (98 entries).
__global__ void __launch_bounds__(128) k_scanB(int* __restrict__ bsum) {
    __shared__ int sh[128];
    const int t = threadIdx.x;
    int v = (t < SCAN_NB) ? bsum[t] : 0;
    sh[t] = v;
    __syncthreads();
    for (int o = 1; o < 128; o <<= 1) {
        int x = (t >= o) ? sh[t - o] : 0;
        __syncthreads();
        sh[t] += x;
        __syncthreads();
    }
    if (t < SCAN_NB) bsum[t] = sh[t] - v;   // exclusive
}

// C: per-block local exclusive scan + block offset, int4 stores.
__global__ void __launch_bounds__(256) k_scanC(const int* __restrict__ cnt,
                                               const int* __restrict__ bsum,
                                               int* __restrict__ off) {
    __shared__ int sh[256];
    const int t = threadIdx.x;
    const int base = blockIdx.x * SCAN_BLK + t * 4;
    int a0 = 0, a1 = 0, a2 = 0, a3 = 0;
    if (base + 3 < NN) {
        const int4 v = *(const int4*)(cnt + base);
        a0 = v.x; a1 = v.y; a2 = v.z; a3 = v.w;
    } else {
        if (base + 0 < NN) a0 = cnt[base + 0];
        if (base + 1 < NN) a1 = cnt[base + 1];
        if (base + 2 < NN) a2 = cnt[base + 2];
    }
    const int s = a0 + a1 + a2 + a3;
    sh[t] = s;
    __syncthreads();
    for (int o = 1; o < 256; o <<= 1) {
        int x = (t >= o) ? sh[t - o] : 0;
        __syncthreads();
        sh[t] += x;
        __syncthreads();
    }
    int ex = sh[t] - s + bsum[blockIdx.x];
    if (base + 3 < NN) {
        int4 w; w.x = ex; w.y = ex + a0; w.z = ex + a0 + a1; w.w = ex + a0 + a1 + a2;
        *(int4*)(off + base) = w;
    } else {
        if (base + 0 < NN) off[base + 0] = ex;
        if (base + 1 < NN) off[base + 1] = ex + a0;
        if (base + 2 < NN) off[base + 2] = ex + a0 + a1;
    }
}

// Phase 0d: place packed keys (t*EE+e)<<1 | side into per-node unordered lists.
__global__ void k_place(const int* __restrict__ edges,
                        const int* __restrict__ off, int* __restrict__ cur,
                        unsigned* __restrict__ ent) {
    int i = blockIdx.x * blockDim.x + threadIdx.x;
    if (i < NE) {
        int s = edges[3 * i + 2];
        if (s) {
            int u = edges[3 * i + 0];
            int v = edges[3 * i + 1];
            unsigned key = ((unsigned)i) << 1;
            ent[off[u] + atomicAdd(&cur[u], 1)] = key;        // side 0: -md
            ent[off[v] + atomicAdd(&cur[v], 1)] = key | 1u;   // side 1: +md
        }
    }
}

// Phase 0e: sort each node's list (keys unique -> deterministic). c ~ 5 avg.
__global__ void k_sort(const int* __restrict__ off, const int* __restrict__ cur,
                       unsigned* __restrict__ ent) {
    int n = blockIdx.x * blockDim.x + threadIdx.x;
    if (n >= NN) return;
    int lo = off[n], c = cur[n];
    for (int k = 1; k < c; ++k) {
        unsigned key = ent[lo + k];
        int j = k;
        while (j > 0 && ent[lo + j - 1] > key) {
            ent[lo + j] = ent[lo + j - 1];
            --j;
        }
        ent[lo + j] = key;
    }
}

// Phase 1: dataflow evaluation. One thread per edge; chunks processed in
// increasing global order. DEADLOCK-SAFE SPIN: one flattened poll loop with a
// per-lane state machine — a lane that becomes ready PUBLISHES INSIDE the
// loop body, so same-wave dependents see it on their next poll iteration.
// Launched cooperatively -> all blocks resident.
__global__ void __launch_bounds__(256, 2)
k_flow(const int* __restrict__ edges, const float* __restrict__ theta,
       const float* __restrict__ X0f, const int* __restrict__ off,
       const int* __restrict__ cur, const unsigned* __restrict__ ent,
       unsigned* __restrict__ pub, float* __restrict__ out_kappa) {
    const float eps = sigmoid_f(theta[0]);
    for (int c = blockIdx.x; c < NCHUNK; c += gridDim.x) {
        const int i = (c << 8) + threadIdx.x;
        const int t = i >> 10;                     // i / EE
        const int u = edges[3 * i + 0];
        const int v = edges[3 * i + 1];
        const int s = edges[3 * i + 2];

        const unsigned stepkey = ((unsigned)t) << 11;  // first key of step t

        const int lu = off[u], hu = lu + cur[u];
        const int qu = lower_bound(ent, lu, hu, stepkey);
        const int lv = off[v], hv = lv + cur[v];
        const int qv = lower_bound(ent, lv, hv, stepkey);

        // Locate own entries (s==1 only): linear scan within the step group.
        int mu_ = -1, mv_ = -1;
        if (s) {
            const unsigned ku = ((unsigned)i) << 1;
            mu_ = qu; while (ent[mu_] != ku) ++mu_;
            const unsigned kv = ku | 1u;
            mv_ = qv; while (ent[mv_] != kv) ++mv_;
        }

        // State machine flags.
        bool have_xu = (qu == lu);
        bool have_xv = (qv == lv);
        float xu = have_xu ? X0f[u] : 0.0f;
        float xv = have_xv ? X0f[v] : 0.0f;
        bool kap_done = false;
        bool pu_done = (s == 0);
        bool pv_done = (s == 0);
        float m = 0.0f;

        while (!(kap_done && pu_done && pv_done)) {
            if (!have_xu) {
                unsigned w = try_val(pub, qu - 1);
                if (w != NOTREADY) { xu = __uint_as_float(w); have_xu = true; }
            }
            if (!have_xv) {
                unsigned w = try_val(pub, qv - 1);
                if (w != NOTREADY) { xv = __uint_as_float(w); have_xv = true; }
            }
            if (have_xu && have_xv && !kap_done) {
                float diff = xu - xv;
                m = MU * diff;
                out_kappa[i] = sigmoid_f(RHO * (eps - fabsf(diff)));
                kap_done = true;
            }
            if (kap_done && !pu_done) {
                bool rdy; float baseu = xu;
                if (mu_ == qu) rdy = true;
                else {
                    unsigned w = try_val(pub, mu_ - 1);
                    rdy = (w != NOTREADY);
                    if (rdy) baseu = __uint_as_float(w);
                }
                if (rdy) { publish(pub, mu_, baseu - m); pu_done = true; }
            }
            if (kap_done && !pv_done) {
                bool rdy; float basev = xv;
                if (mv_ == qv) rdy = true;
                else {
                    unsigned w = try_val(pub, mv_ - 1);
                    rdy = (w != NOTREADY);
                    if (rdy) basev = __uint_as_float(w);
                }
                if (rdy) { publish(pub, mv_, basev + m); pv_done = true; }
            }
            if (!(kap_done && pu_done && pv_done)) __builtin_amdgcn_s_sleep(1);
        }
    }
}

// Phase 2 (main): reconstruct X rows from published running values.
// 2-D tiling: block (bx, rc) — threads own 4 consecutive nodes over RB rows.
// Entry into the row chunk: binary search for first key >= r0, start value =
// pub[prev entry] (running value) or X0. float4 stores, fully coalesced.
__global__ void __launch_bounds__(256) k_fill_pub(float* __restrict__ out,
                                                  const float* __restrict__ X0f,
                                                  const int* __restrict__ off,
                                                  const int* __restrict__ cur,
                                                  const unsigned* __restrict__ ent,
                                                  const unsigned* __restrict__ pub) {
    const int n0 = (blockIdx.x * 256 + threadIdx.x) * 4;
    if (n0 >= NN) return;                  // NN % 4 == 0: full float4 valid
    const int r0 = blockIdx.y * RB;
    const unsigned key0 = ((unsigned)r0) << 11;

    int   p[4], e2[4];
    unsigned nxt[4];
    float val[4];
    #pragma unroll
    for (int j = 0; j < 4; ++j) {
        const int n = n0 + j;
        const int lo = off[n];
        e2[j] = lo + cur[n];
        int q = lower_bound(ent, lo, e2[j], key0);
        val[j] = (q > lo) ? __uint_as_float(pub[q - 1]) : X0f[n];
        p[j] = q;
        nxt[j] = (q < e2[j]) ? ent[q] : 0xFFFFFFFFu;
    }

    const int rstart = (r0 == 0) ? 1 : r0;   // row 0 written by k_init
    for (int r = rstart; r < r0 + RB; ++r) {
        const unsigned lim = ((unsigned)r) << 11;   // keys with t < r
        #pragma unroll
        for (int j = 0; j < 4; ++j) {
            while (nxt[j] < lim) {
                val[j] = __uint_as_float(pub[p[j]]);
                ++p[j];
                nxt[j] = (p[j] < e2[j]) ? ent[p[j]] : 0xFFFFFFFFu;
            }
        }
        float4 w; w.x = val[0]; w.y = val[1]; w.z = val[2]; w.w = val[3];
        *(float4*)(out + (size_t)r * NN + n0) = w;
    }
}

// ---------- fallback path (proven R3, 2.26 ms): sequential scan ----------
__global__ void __launch_bounds__(1024) k_seq(const int* __restrict__ edges,
                                              const float* __restrict__ theta,
                                              float* __restrict__ X,
                                              float* __restrict__ out_kappa,
                                              float* __restrict__ md) {
    const int tid = threadIdx.x;
    const float eps = sigmoid_f(theta[0]);
    int u = edges[3 * tid + 0];
    int v = edges[3 * tid + 1];
    int s = edges[3 * tid + 2];
    for (int t = 0; t < NSTEP; ++t) {
        int nu = 0, nv = 0, ns = 0;
        if (t + 1 < NSTEP) {
            const int nb = (t + 1) * 3 * EE + 3 * tid;
            nu = edges[nb + 0]; nv = edges[nb + 1]; ns = edges[nb + 2];
        }
        float xu = __hip_atomic_load(&X[u], RLX, WGS);
        float xv = __hip_atomic_load(&X[v], RLX, WGS);
        float diff = xu - xv;
        out_kappa[t * EE + tid] = sigmoid_f(RHO * (eps - fabsf(diff)));
        bool act = (s && diff != 0.0f);
        float m = act ? MU * diff : 0.0f;
        md[t * EE + tid] = m;
        __syncthreads();
        if (act) {
            __hip_atomic_fetch_add(&X[u], -m, RLX, WGS);
            __hip_atomic_fetch_add(&X[v],  m, RLX, WGS);
        }
        __syncthreads();
        u = nu; v = nv; s = ns;
    }
}

__global__ void k_fill_md(float* __restrict__ out,
                          const int* __restrict__ off, const int* __restrict__ cur,
                          const unsigned* __restrict__ ent,
                          const float* __restrict__ md) {
    int n = blockIdx.x * blockDim.x + threadIdx.x;
    if (n >= NN) return;
    float val = out[n];
    int p = off[n];
    const int e2 = p + cur[n];
    unsigned nxt = (p < e2) ? ent[p] : 0xFFFFFFFFu;
    for (int r = 1; r < TT; ++r) {
        const unsigned lim = ((unsigned)r) << 11;
        while (nxt < lim) {
            float m = md[nxt >> 1];
            val += (nxt & 1u) ? m : -m;
            ++p;
            nxt = (p < e2) ? ent[p] : 0xFFFFFFFFu;
        }
        out[(size_t)r * NN + n] = val;
    }
}
// ---------------------------------------------------------------------------

extern "C" void kernel_launch(void* const* d_in, const int* in_sizes, int n_in,
                              void* d_out, int out_size, void* d_ws, size_t ws_size,
                              hipStream_t stream) {
    const float* logit = (const float*)d_in[0];
    const float* theta = (const float*)d_in[1];
    const int*   edges = (const int*)d_in[2];
    float* out = (float*)d_out;
    float* kap = out + (size_t)TT * NN;

    char* ws = (char*)d_ws;
    float*    X0f  = (float*)ws;    ws += sizeof(float) * NN;
    int*      cnt  = (int*)ws;      ws += sizeof(int) * NN;
    int*      off  = (int*)ws;      ws += sizeof(int) * NN;
    int*      cur  = (int*)ws;      ws += sizeof(int) * NN;
    int*      bsum = (int*)ws;      ws += sizeof(int) * ((SCAN_NB + 3) & ~3);
    unsigned* ent  = (unsigned*)ws; ws += sizeof(unsigned) * CAP;
    // main path uses pub (CAP u32); fallback uses md (NE f32). They overlap.
    unsigned* pub = (unsigned*)ws;
    float*    md  = (float*)ws;

    const size_t need_main = (size_t)(4 * NN + SCAN_NB + 3) * 4
                           + (size_t)CAP * 4 * 2;
    const bool main_path = ws_size >= need_main;

    k_init <<<(NN + 255) / 256, 256, 0, stream>>>(logit, X0f, out, cnt, cur);
    k_count<<<(NE + 255) / 256, 256, 0, stream>>>(edges, cnt, pub);
    k_scanA<<<SCAN_NB, 256, 0, stream>>>(cnt, bsum);
    k_scanB<<<1, 128, 0, stream>>>(bsum);
    k_scanC<<<SCAN_NB, 256, 0, stream>>>(cnt, bsum, off);
    k_place<<<(NE + 255) / 256, 256, 0, stream>>>(edges, off, cur, ent);
    k_sort <<<(NN + 255) / 256, 256, 0, stream>>>(off, cur, ent);

    bool flow_ok = false;
    if (main_path) {
        const int* a_edges = edges; const float* a_theta = theta;
        const float* a_x0 = X0f; const int* a_off = off; const int* a_cur = cur;
        const unsigned* a_ent = ent; unsigned* a_pub = pub; float* a_kap = kap;
        void* args[] = { &a_edges, &a_theta, &a_x0, &a_off, &a_cur,
                         &a_ent, &a_pub, &a_kap };
        hipError_t e = hipLaunchCooperativeKernel((const void*)k_flow,
                                                  dim3(FLOWG), dim3(256),
                                                  args, 0, stream);
        if (e == hipSuccess) {
            flow_ok = true;
            k_fill_pub<<<dim3(FILL_BX, NRC), 256, 0, stream>>>(out, X0f, off,
                                                               cur, ent, pub);
        } else {
            (void)hipGetLastError();
        }
    }
    if (!flow_ok) {
        // Proven sequential path (R3): single-block scan + delta fill.
        k_seq<<<1, 1024, 0, stream>>>(edges, theta, X0f, kap, md);
        k_fill_md<<<(NN + 255) / 256, 256, 0, stream>>>(out, off, cur, ent, md);
    }
}